// Round 7
// baseline (352.453 us; speedup 1.0000x reference)
//
#include <hip/hip_runtime.h>
#include <math.h>

#define NN 16384
#define EE 262144

typedef __bf16 v8bf __attribute__((ext_vector_type(8)));
typedef __bf16 v4bf __attribute__((ext_vector_type(4)));
typedef float  v4f  __attribute__((ext_vector_type(4)));
typedef float  v2f  __attribute__((ext_vector_type(2)));

// ---- workspace layout (units of 4-byte elements) ----
#define OFF_CNT     0                         // 2*NN ints
#define OFF_FILL    (2*NN)                    // 2*NN ints
#define OFF_ROWPTR  (4*NN)                    // 2*(NN+1) ints
#define OFF_COLSRC  98816                     // 2*EE ints (byte offsets)
#define OFF_H       623104                    // 2*NN*64 f32
#define OFF_HN      (OFF_H  + 2*NN*64)        // 2*NN*64 f32
#define OFF_Q       (OFF_HN + 2*NN*64)        // 2*NN*256 bf16 (512B rows)
#define OFF_KV      (OFF_Q  + 2*NN*128)       // 2*NN rows of 512 B (K fp8 256B | V fp8 256B)
#define OFF_R       (OFF_KV + 2*NN*128)       // 2*NN*64 f32
#define OFF_WT      (OFF_R  + 2*NN*64)        // transposed bf16 weights (ushort base)

// bf16-element offsets inside WT area
#define WT_Q   0         // [4][256*64]
#define WT_K   65536
#define WT_V   131072
#define WT_S   196608    // [4][64*64]
#define WT_IN  212992    // [2][64*64]
#define WT_W1  221184    // [4][256*64]
#define WT_W2  286720    // [4][64*256]
#define WT_WO  352256    // [2][64*64]

__device__ __forceinline__ float blo(unsigned u) { return __uint_as_float(u << 16); }
__device__ __forceinline__ float bhi(unsigned u) { return __uint_as_float(u & 0xffff0000u); }
__device__ __forceinline__ unsigned short f2b(float f) {
  __bf16 h = (__bf16)f;
  return *(unsigned short*)&h;
}

// ======================= weight prep: f32 [K][N] -> bf16 [N][K] =======================
struct PrepDesc { const float* src; unsigned short* dst; int ksh; int total; };
struct PrepPack { PrepDesc d[28]; };

__global__ __launch_bounds__(256) void prep_kernel(PrepPack p) {
  PrepDesc g = p.d[blockIdx.y];
  int idx = blockIdx.x * 256 + threadIdx.x;
  if (idx >= g.total) return;
  int K = 1 << g.ksh;
  int n = idx >> g.ksh;
  int k = idx & (K - 1);
  int N = g.total >> g.ksh;
  g.dst[idx] = f2b(g.src[(size_t)k * N + n]);
}

// ======================= CSR build =======================
__global__ void count_kernel(const int* __restrict__ ei, int* __restrict__ cnt) {
  int idx = blockIdx.x * 256 + threadIdx.x;
  if (idx >= 2 * EE) return;
  int et = idx >> 18;
  int j  = idx & (EE - 1);
  int dst = ei[et * 2 * EE + EE + j];
  atomicAdd(&cnt[et * NN + dst], 1);
}

__global__ __launch_bounds__(1024) void scan_kernel(const int* __restrict__ cnt,
                                                    int* __restrict__ rowptr,
                                                    int* __restrict__ fill) {
  int et = blockIdx.x;
  const int* c = cnt + et * NN;
  __shared__ int sums[1024];
  int tid = threadIdx.x;
  int base = tid * 16;
  int loc[16];
  int s = 0;
#pragma unroll
  for (int i = 0; i < 16; ++i) { loc[i] = s; s += c[base + i]; }
  sums[tid] = s;
  __syncthreads();
  for (int off = 1; off < 1024; off <<= 1) {
    int v = 0;
    if (tid >= off) v = sums[tid - off];
    __syncthreads();
    if (tid >= off) sums[tid] += v;
    __syncthreads();
  }
  int ebase = (tid == 0) ? 0 : sums[tid - 1];
  int* rp = rowptr + et * (NN + 1);
  int* fl = fill + et * NN;
#pragma unroll
  for (int i = 0; i < 16; ++i) {
    rp[base + i] = ebase + loc[i];
    fl[base + i] = ebase + loc[i];
  }
  if (tid == 1023) rp[NN] = sums[1023];
}

// colsrc holds BYTE offset of the src node's KV row: (et*NN + src) * 512
__global__ void scatter_kernel(const int* __restrict__ ei, int* __restrict__ fill,
                               int* __restrict__ colsrc) {
  int idx = blockIdx.x * 256 + threadIdx.x;
  if (idx >= 2 * EE) return;
  int et = idx >> 18;
  int j  = idx & (EE - 1);
  int src = ei[et * 2 * EE + j];
  int dst = ei[et * 2 * EE + EE + j];
  int pos = atomicAdd(&fill[et * NN + dst], 1);
  colsrc[et * EE + pos] = (et * NN + src) << 9;
}

// ======================= bf16 MFMA tiled GEMM (A in REGISTERS, Bt pre-transposed) =======================
// K=64 fixed. Bt is bf16 [Ncols][64]. otype: 0=f32, 1=bf16, 2=fp8. Cld = C row stride in BYTES.
// A fragments are wave-private (each wave owns 32 rows) -> kept in 16 VGPRs, no As LDS,
// no A-stage barrier, no per-tile A ds_reads. Bs stays LDS (shared across waves).
struct GemmDesc {
  const float *A, *bias, *bias2, *add;
  const unsigned short* Bt;
  char* C;
  int Ncols, Cld, ntiles, gelu, otype;
};
struct GemmPack { GemmDesc d[8]; int nd; };

#define LDA 72   // padded bf16 row stride

__global__ __launch_bounds__(256) void gemm_mfma(GemmPack p) {
  GemmDesc g = p.d[blockIdx.y];
  const int row0 = blockIdx.x * 128;
  const int tid = threadIdx.x;
  const int w = tid >> 6, lane = tid & 63;
  const int l16 = lane & 15, quad = lane >> 4;

  __shared__ __bf16 Bs[64 * LDA];

  // A fragments once into registers: wave w owns rows row0 + w*32 .. +31
  v8bf afr[2][2];   // [rt][ks]
#pragma unroll
  for (int rt = 0; rt < 2; ++rt)
#pragma unroll
    for (int ks = 0; ks < 2; ++ks) {
      const float* ap = g.A + (size_t)(row0 + w * 32 + rt * 16 + l16) * 64 + ks * 32 + quad * 8;
      float4 x0 = *(const float4*)ap;
      float4 x1 = *(const float4*)(ap + 4);
      v8bf f = { (__bf16)x0.x, (__bf16)x0.y, (__bf16)x0.z, (__bf16)x0.w,
                 (__bf16)x1.x, (__bf16)x1.y, (__bf16)x1.z, (__bf16)x1.w };
      afr[rt][ks] = f;
    }

  const int brow = tid >> 2;          // 0..63 (B tile row)
  const int bko  = (tid & 3) << 4;    // k chunk: 0,16,32,48 (bf16 elems)

  for (int ct0 = 0; ct0 < g.ntiles; ++ct0) {
    const int col0 = ct0 * 64;
    if (ct0 > 0) __syncthreads();   // prior MFMA done reading Bs
    {
      const unsigned short* bp = g.Bt + (size_t)(col0 + brow) * 64 + bko;
      uint4 b0 = *(const uint4*)(bp);
      uint4 b1 = *(const uint4*)(bp + 8);
      *(uint4*)&Bs[brow * LDA + bko] = b0;
      *(uint4*)&Bs[brow * LDA + bko + 8] = b1;
    }
    __syncthreads();

    v4f acc[2][4];
#pragma unroll
    for (int rt = 0; rt < 2; ++rt)
#pragma unroll
      for (int ct = 0; ct < 4; ++ct)
#pragma unroll
        for (int r = 0; r < 4; ++r) acc[rt][ct][r] = 0.f;

#pragma unroll
    for (int ks = 0; ks < 2; ++ks) {
#pragma unroll
      for (int ct = 0; ct < 4; ++ct) {
        v8bf bb = *(v8bf*)&Bs[(ct * 16 + l16) * LDA + ks * 32 + quad * 8];
        acc[0][ct] = __builtin_amdgcn_mfma_f32_16x16x32_bf16(afr[0][ks], bb, acc[0][ct], 0, 0, 0);
        acc[1][ct] = __builtin_amdgcn_mfma_f32_16x16x32_bf16(afr[1][ks], bb, acc[1][ct], 0, 0, 0);
      }
    }

    float bias_c[4];
#pragma unroll
    for (int ct = 0; ct < 4; ++ct) {
      int col = col0 + ct * 16 + l16;
      float b = g.bias ? g.bias[col] : 0.f;
      if (g.bias2) b += g.bias2[col];
      bias_c[ct] = b;
    }
#pragma unroll
    for (int rt = 0; rt < 2; ++rt)
#pragma unroll
      for (int r = 0; r < 4; ++r) {
        size_t row = row0 + w * 32 + rt * 16 + quad * 4 + r;
        char* cp = g.C + row * (size_t)g.Cld;
#pragma unroll
        for (int ct = 0; ct < 4; ++ct) {
          int col = col0 + ct * 16 + l16;
          float v = acc[rt][ct][r] + bias_c[ct];
          if (g.add) v += g.add[row * g.Ncols + col];
          if (g.gelu) v = 0.5f * v * (1.f + erff(v * 0.70710678118654752f));
          if (g.otype == 0)      *(float*)(cp + col * 4) = v;
          else if (g.otype == 1) *(unsigned short*)(cp + col * 2) = f2b(v);
          else {
            unsigned pk = __builtin_amdgcn_cvt_pk_fp8_f32(v, v, 0, false);
            *(unsigned char*)(cp + col) = (unsigned char)(pk & 0xff);
          }
        }
      }
  }
}

// ======================= fused FF (A in regs) + optional fused out-proj =======================
struct FFPack {
  const float *HN;
  const unsigned short *W1t, *W2t, *Wot;   // bf16 [n][k] transposed, per-type blocks
  const float *b1, *b2, *bout;
  float* H;
  float* outbuf;              // if non-null: write out = H@Wout+bout, skip H store
};

__global__ __launch_bounds__(256) void ff_fused(FFPack p) {
  const int t = blockIdx.y;
  const int row0 = blockIdx.x * 64;
  const int tid = threadIdx.x;
  const int w = tid >> 6, lane = tid & 63;
  const int l16 = lane & 15, quad = lane >> 4;

  const float* A  = p.HN + ((size_t)t * NN) * 64;
  const unsigned short* W1t = p.W1t + (size_t)t * 16384;  // [256][64]
  const unsigned short* W2t = p.W2t + (size_t)t * 16384;  // [64][256]
  const float* b1 = p.b1 + t * 256;
  const float* b2 = p.b2 + t * 64;

  __shared__ __bf16 A2[64 * LDA];
  __shared__ __bf16 B1s[64 * LDA];
  __shared__ __bf16 B2s[64 * LDA];

  // A fragments once into registers: wave w owns rows row0 + w*16 .. +15
  v8bf afr[2];
#pragma unroll
  for (int ks = 0; ks < 2; ++ks) {
    const float* ap = A + (size_t)(row0 + w * 16 + l16) * 64 + ks * 32 + quad * 8;
    float4 x0 = *(const float4*)ap;
    float4 x1 = *(const float4*)(ap + 4);
    v8bf f = { (__bf16)x0.x, (__bf16)x0.y, (__bf16)x0.z, (__bf16)x0.w,
               (__bf16)x1.x, (__bf16)x1.y, (__bf16)x1.z, (__bf16)x1.w };
    afr[ks] = f;
  }

  const int brow = tid >> 2;          // 0..63
  const int bko  = (tid & 3) << 4;    // 0,16,32,48

  v4f acc2[4];
#pragma unroll
  for (int ct = 0; ct < 4; ++ct)
#pragma unroll
    for (int r = 0; r < 4; ++r) acc2[ct][r] = 0.f;

  for (int c1 = 0; c1 < 4; ++c1) {
    if (c1 > 0) __syncthreads();   // prior MFMA done reading B1s/B2s
    {
      const unsigned short* bp1 = W1t + (size_t)(c1 * 64 + brow) * 64 + bko;
      uint4 u0 = *(const uint4*)(bp1);
      uint4 u1 = *(const uint4*)(bp1 + 8);
      *(uint4*)&B1s[brow * LDA + bko] = u0;
      *(uint4*)&B1s[brow * LDA + bko + 8] = u1;
      const unsigned short* bp2 = W2t + (size_t)brow * 256 + c1 * 64 + bko;
      uint4 u2 = *(const uint4*)(bp2);
      uint4 u3 = *(const uint4*)(bp2 + 8);
      *(uint4*)&B2s[brow * LDA + bko] = u2;
      *(uint4*)&B2s[brow * LDA + bko + 8] = u3;
    }
    __syncthreads();

    v4f acc1[4];
#pragma unroll
    for (int ct = 0; ct < 4; ++ct)
#pragma unroll
      for (int r = 0; r < 4; ++r) acc1[ct][r] = 0.f;
#pragma unroll
    for (int ks = 0; ks < 2; ++ks) {
#pragma unroll
      for (int ct = 0; ct < 4; ++ct) {
        v8bf bb = *(v8bf*)&B1s[(ct * 16 + l16) * LDA + ks * 32 + quad * 8];
        acc1[ct] = __builtin_amdgcn_mfma_f32_16x16x32_bf16(afr[ks], bb, acc1[ct], 0, 0, 0);
      }
    }
#pragma unroll
    for (int ct = 0; ct < 4; ++ct) {
      float bb = b1[c1 * 64 + ct * 16 + l16];
#pragma unroll
      for (int r = 0; r < 4; ++r) {
        float v = acc1[ct][r] + bb;
        v = 0.5f * v * (1.f + erff(v * 0.70710678118654752f));
        A2[(w * 16 + quad * 4 + r) * LDA + ct * 16 + l16] = (__bf16)v;
      }
    }
    // wave-private 16-row slice: compiler-inserted lgkmcnt orders the RAW
#pragma unroll
    for (int ks = 0; ks < 2; ++ks) {
      v8bf a = *(v8bf*)&A2[(w * 16 + l16) * LDA + ks * 32 + quad * 8];
#pragma unroll
      for (int ct = 0; ct < 4; ++ct) {
        v8bf bb = *(v8bf*)&B2s[(ct * 16 + l16) * LDA + ks * 32 + quad * 8];
        acc2[ct] = __builtin_amdgcn_mfma_f32_16x16x32_bf16(a, bb, acc2[ct], 0, 0, 0);
      }
    }
  }

  if (!p.outbuf) {
    // standard epilogue: H = hr + acc2 + b2
#pragma unroll
    for (int ct = 0; ct < 4; ++ct) {
      int col = ct * 16 + l16;
      float bb = b2[col];
#pragma unroll
      for (int r = 0; r < 4; ++r) {
        size_t row = (size_t)t * NN + row0 + w * 16 + quad * 4 + r;
        float v = acc2[ct][r] + bb + p.HN[row * 64 + col];
        p.H[row * 64 + col] = v;
      }
    }
    return;
  }

  // ---- fused output projection (last layer): out = (hr+ff) @ Wout + bout ----
  __syncthreads();   // all waves done reading B1s before restage
#pragma unroll
  for (int ct = 0; ct < 4; ++ct) {
    int col = ct * 16 + l16;
    float bb = b2[col];
#pragma unroll
    for (int r = 0; r < 4; ++r) {
      int lrow = w * 16 + quad * 4 + r;
      size_t row = (size_t)t * NN + row0 + lrow;
      float v = acc2[ct][r] + bb + p.HN[row * 64 + col];
      A2[lrow * LDA + col] = (__bf16)v;
    }
  }
  {
    const unsigned short* Wot = p.Wot + (size_t)t * 4096;  // [64][64]
    const unsigned short* bp = Wot + (size_t)brow * 64 + bko;
    uint4 u0 = *(const uint4*)(bp);
    uint4 u1 = *(const uint4*)(bp + 8);
    *(uint4*)&B1s[brow * LDA + bko] = u0;
    *(uint4*)&B1s[brow * LDA + bko + 8] = u1;
  }
  __syncthreads();

  v4f acc3[4];
#pragma unroll
  for (int ct = 0; ct < 4; ++ct)
#pragma unroll
    for (int r = 0; r < 4; ++r) acc3[ct][r] = 0.f;
#pragma unroll
  for (int ks = 0; ks < 2; ++ks) {
    v8bf a = *(v8bf*)&A2[(w * 16 + l16) * LDA + ks * 32 + quad * 8];
#pragma unroll
    for (int ct = 0; ct < 4; ++ct) {
      v8bf bb = *(v8bf*)&B1s[(ct * 16 + l16) * LDA + ks * 32 + quad * 8];
      acc3[ct] = __builtin_amdgcn_mfma_f32_16x16x32_bf16(a, bb, acc3[ct], 0, 0, 0);
    }
  }
  const float* bo = p.bout + t * 64;
#pragma unroll
  for (int ct = 0; ct < 4; ++ct) {
    int col = ct * 16 + l16;
    float bb = bo[col];
#pragma unroll
    for (int r = 0; r < 4; ++r) {
      size_t row = (size_t)t * NN + row0 + w * 16 + quad * 4 + r;
      p.outbuf[row * 64 + col] = acc3[ct][r] + bb;
    }
  }
}

// ======================= edge aggregation + beta + LN (R3 form: grid.y = edge type) =======================
// One wave / dst node; lane = head*16 + c4.
// KV row 512 B: K fp8 [0,256) | V fp8 [256,512). No-max softmax, 4 uniform streams.
struct AggPack {
  const unsigned short *Q;   // [2*NN][256] bf16 (dst-type indexed)
  const char *KV;            // [2*NN] rows of 512 B (src-type indexed)
  const float *R;            // [2*NN][64]
  const float *Wb;
  const float *Hin;
  const float *lng, *lnb;
  float* outHR;
  const int *rowptr;
  const int *colsrc;         // byte offsets
};

__global__ __launch_bounds__(256) void agg_kernel(AggPack p) {
  const int et = blockIdx.y, d = 1 - et;
  int wid = __builtin_amdgcn_readfirstlane(threadIdx.x >> 6);
  int lane = threadIdx.x & 63;
  int node = blockIdx.x * 4 + wid;
  int c4 = lane & 15;
  int cb = ((lane >> 4) << 6) + (c4 << 2);   // channel index: head*64 + c4*4

  const int* rp = p.rowptr + et * (NN + 1);
  const int* cs = p.colsrc + et * EE;
  int start = rp[node], end = rp[node + 1];
  int len = end - start;
  int gnode = d * NN + node;

  uint2 qw = *(const uint2*)(p.Q + ((size_t)gnode << 8) + cb);
  float q0 = blo(qw.x) * 0.125f, q1 = bhi(qw.x) * 0.125f;
  float q2 = blo(qw.y) * 0.125f, q3 = bhi(qw.y) * 0.125f;

  int b[5];
#pragma unroll
  for (int i = 0; i <= 4; ++i) b[i] = start + ((len * i) >> 2);
  float dsum[4] = {0.f, 0.f, 0.f, 0.f};
  float acc[4][4];
#pragma unroll
  for (int s4 = 0; s4 < 4; ++s4)
#pragma unroll
    for (int c = 0; c < 4; ++c) acc[s4][c] = 0.f;

  int maxn = (len + 3) >> 2;
  int last = end - 1;
  for (int it = 0; it < maxn; ++it) {
#pragma unroll
    for (int s4 = 0; s4 < 4; ++s4) {
      int j = b[s4] + it;
      bool act = j < b[s4 + 1];
      int jc = act ? j : last;
      int off = cs[jc];                      // KV row byte offset
      const char* rowp = p.KV + off;
      unsigned kw = *(const unsigned*)(rowp + cb);          // 4 fp8 K vals
      unsigned vw = *(const unsigned*)(rowp + 256 + cb);    // 4 fp8 V vals
      v2f kl = __builtin_amdgcn_cvt_pk_f32_fp8((int)kw, false);
      v2f kh = __builtin_amdgcn_cvt_pk_f32_fp8((int)kw, true);
      float pd = q0 * kl[0] + q1 * kl[1] + q2 * kh[0] + q3 * kh[1];
      pd += __shfl_xor(pd, 1);
      pd += __shfl_xor(pd, 2);
      pd += __shfl_xor(pd, 4);
      pd += __shfl_xor(pd, 8);
      float wgt = act ? __expf(pd) : 0.f;
      v2f vl = __builtin_amdgcn_cvt_pk_f32_fp8((int)vw, false);
      v2f vh = __builtin_amdgcn_cvt_pk_f32_fp8((int)vw, true);
      dsum[s4] += wgt;
      acc[s4][0] += wgt * vl[0];
      acc[s4][1] += wgt * vl[1];
      acc[s4][2] += wgt * vh[0];
      acc[s4][3] += wgt * vh[1];
    }
  }
  // exact stream merge
  float dn = (dsum[0] + dsum[1]) + (dsum[2] + dsum[3]);
  float ax = (acc[0][0] + acc[1][0]) + (acc[2][0] + acc[3][0]);
  float ay = (acc[0][1] + acc[1][1]) + (acc[2][1] + acc[3][1]);
  float az = (acc[0][2] + acc[1][2]) + (acc[2][2] + acc[3][2]);
  float aw = (acc[0][3] + acc[1][3]) + (acc[2][3] + acc[3][3]);

  float inv = (len > 0) ? (0.25f / dn) : 0.f;
  float ox = ax * inv, oy = ay * inv, oz = az * inv, ow = aw * inv;
  ox += __shfl_xor(ox, 16); ox += __shfl_xor(ox, 32);
  oy += __shfl_xor(oy, 16); oy += __shfl_xor(oy, 32);
  oz += __shfl_xor(oz, 16); oz += __shfl_xor(oz, 32);
  ow += __shfl_xor(ow, 16); ow += __shfl_xor(ow, 32);

  int cc = c4 << 2;
  float4 r = *(const float4*)(p.R + (size_t)gnode * 64 + cc);
  const float* wb = p.Wb + et * 192;
  float part = ox * wb[cc] + oy * wb[cc + 1] + oz * wb[cc + 2] + ow * wb[cc + 3]
             + r.x * wb[64 + cc] + r.y * wb[64 + cc + 1]
             + r.z * wb[64 + cc + 2] + r.w * wb[64 + cc + 3]
             + (ox - r.x) * wb[128 + cc] + (oy - r.y) * wb[128 + cc + 1]
             + (oz - r.z) * wb[128 + cc + 2] + (ow - r.w) * wb[128 + cc + 3];
  part += __shfl_xor(part, 1);
  part += __shfl_xor(part, 2);
  part += __shfl_xor(part, 4);
  part += __shfl_xor(part, 8);
  float beta = 1.f / (1.f + __expf(-part));

  float4 hv = *(const float4*)(p.Hin + (size_t)gnode * 64 + cc);
  float yx = hv.x + beta * r.x + (1.f - beta) * ox;
  float yy = hv.y + beta * r.y + (1.f - beta) * oy;
  float yz = hv.z + beta * r.z + (1.f - beta) * oz;
  float yw = hv.w + beta * r.w + (1.f - beta) * ow;
  float sa = yx + yy + yz + yw;
  float sb = yx * yx + yy * yy + yz * yz + yw * yw;
  sa += __shfl_xor(sa, 1); sb += __shfl_xor(sb, 1);
  sa += __shfl_xor(sa, 2); sb += __shfl_xor(sb, 2);
  sa += __shfl_xor(sa, 4); sb += __shfl_xor(sb, 4);
  sa += __shfl_xor(sa, 8); sb += __shfl_xor(sb, 8);
  float mu = sa * (1.f / 64.f);
  float var = sb * (1.f / 64.f) - mu * mu;
  float rs = rsqrtf(var + 1e-5f);
  if (lane < 16) {
    const float* lng = p.lng + d * 64;
    const float* lnb = p.lnb + d * 64;
    float4 gg = *(const float4*)(lng + cc);
    float4 bb = *(const float4*)(lnb + cc);
    float4 res;
    res.x = (yx - mu) * rs * gg.x + bb.x;
    res.y = (yy - mu) * rs * gg.y + bb.y;
    res.z = (yz - mu) * rs * gg.z + bb.z;
    res.w = (yw - mu) * rs * gg.w + bb.w;
    *(float4*)(p.outHR + (size_t)gnode * 64 + cc) = res;
  }
}

// ======================= host =======================
static void add_desc(GemmPack& p, const float* A, const unsigned short* Bt,
                     const float* bias, const float* bias2, const float* add,
                     void* C, int Nc, int Cld, int gelu, int otype) {
  GemmDesc& g = p.d[p.nd++];
  g.A = A; g.Bt = Bt; g.bias = bias; g.bias2 = bias2; g.add = add; g.C = (char*)C;
  g.Ncols = Nc; g.Cld = Cld; g.ntiles = Nc / 64;
  g.gelu = gelu; g.otype = otype;
}

extern "C" void kernel_launch(void* const* d_in, const int* in_sizes, int n_in,
                              void* d_out, int out_size, void* d_ws, size_t ws_size,
                              hipStream_t stream) {
  const float* x        = (const float*)d_in[0];
  const int*   ei       = (const int*)d_in[1];
  const float* W_in     = (const float*)d_in[2];
  const float* b_in     = (const float*)d_in[3];
  const float* type_emb = (const float*)d_in[4];
  const float* pos      = (const float*)d_in[5];
  const float* Wq       = (const float*)d_in[6];
  const float* bq       = (const float*)d_in[7];
  const float* Wk       = (const float*)d_in[8];
  const float* bk       = (const float*)d_in[9];
  const float* Wv       = (const float*)d_in[10];
  const float* bv       = (const float*)d_in[11];
  const float* Wskip    = (const float*)d_in[12];
  const float* bskip    = (const float*)d_in[13];
  const float* Wbeta    = (const float*)d_in[14];
  const float* ln_g     = (const float*)d_in[15];
  const float* ln_b     = (const float*)d_in[16];
  const float* ff_W1    = (const float*)d_in[17];
  const float* ff_b1    = (const float*)d_in[18];
  const float* ff_W2    = (const float*)d_in[19];
  const float* ff_b2    = (const float*)d_in[20];
  const float* W_out    = (const float*)d_in[21];
  const float* b_out    = (const float*)d_in[22];
  float* out = (float*)d_out;

  int*   wsi = (int*)d_ws;
  float* wsf = (float*)d_ws;
  int* cnt    = wsi + OFF_CNT;
  int* fill   = wsi + OFF_FILL;
  int* rowptr = wsi + OFF_ROWPTR;
  int* colsrc = wsi + OFF_COLSRC;
  float* H  = wsf + OFF_H;
  float* HN = wsf + OFF_HN;
  unsigned short* Qb = (unsigned short*)(wsf + OFF_Q);
  char* KVb = (char*)(wsf + OFF_KV);
  float* Rb = wsf + OFF_R;
  unsigned short* wt = (unsigned short*)(wsf + OFF_WT);

  // ---- weight prep (transpose + bf16), once per launch ----
  {
    PrepPack pp{};
    int nd = 0;
    for (int we = 0; we < 4; ++we) {
      pp.d[nd++] = { Wq + (size_t)we * 16384, wt + WT_Q + we * 16384, 6, 16384 };
      pp.d[nd++] = { Wk + (size_t)we * 16384, wt + WT_K + we * 16384, 6, 16384 };
      pp.d[nd++] = { Wv + (size_t)we * 16384, wt + WT_V + we * 16384, 6, 16384 };
      pp.d[nd++] = { Wskip + (size_t)we * 4096, wt + WT_S + we * 4096, 6, 4096 };
      pp.d[nd++] = { ff_W1 + (size_t)we * 16384, wt + WT_W1 + we * 16384, 6, 16384 };
      pp.d[nd++] = { ff_W2 + (size_t)we * 16384, wt + WT_W2 + we * 16384, 8, 16384 };
    }
    for (int t = 0; t < 2; ++t) {
      pp.d[nd++] = { W_in + (size_t)t * 4096, wt + WT_IN + t * 4096, 6, 4096 };
      pp.d[nd++] = { W_out + (size_t)t * 4096, wt + WT_WO + t * 4096, 6, 4096 };
    }
    prep_kernel<<<dim3(64, nd), dim3(256), 0, stream>>>(pp);
  }

  // ---- CSR build ----
  hipMemsetAsync(cnt, 0, 2 * NN * sizeof(int), stream);
  count_kernel<<<dim3(2 * EE / 256), dim3(256), 0, stream>>>(ei, cnt);
  scan_kernel<<<dim3(2), dim3(1024), 0, stream>>>(cnt, rowptr, fill);
  scatter_kernel<<<dim3(2 * EE / 256), dim3(256), 0, stream>>>(ei, fill, colsrc);

  // ---- input projection ----
  {
    GemmPack p{};
    for (int t = 0; t < 2; ++t)
      add_desc(p, x + (size_t)t * NN * 64, wt + WT_IN + t * 4096,
               b_in + t * 64, type_emb + t * 64, pos + (size_t)t * NN * 64,
               H + (size_t)t * NN * 64, 64, 256, 0, 0);
    gemm_mfma<<<dim3(128, p.nd), dim3(256), 0, stream>>>(p);
  }

  for (int l = 0; l < 2; ++l) {
    // one batched GEMM for both edge types: q,k,v,skip x 2
    {
      GemmPack p{};
      for (int et = 0; et < 2; ++et) {
        int s = et, d = 1 - et;
        int we = l * 2 + et;
        const float* hs = H + (size_t)s * NN * 64;
        const float* hd = H + (size_t)d * NN * 64;
        add_desc(p, hd, wt + WT_Q + we * 16384, bq + we * 256,
                 nullptr, nullptr, (char*)Qb + (size_t)d * NN * 512, 256, 512, 0, 1);
        add_desc(p, hs, wt + WT_K + we * 16384, bk + we * 256,
                 nullptr, nullptr, KVb + (size_t)s * NN * 512, 256, 512, 0, 2);
        add_desc(p, hs, wt + WT_V + we * 16384, bv + we * 256,
                 nullptr, nullptr, KVb + (size_t)s * NN * 512 + 256, 256, 512, 0, 2);
        add_desc(p, hd, wt + WT_S + we * 4096, bskip + we * 64,
                 nullptr, nullptr, Rb + (size_t)d * NN * 64, 64, 256, 0, 0);
      }
      gemm_mfma<<<dim3(128, p.nd), dim3(256), 0, stream>>>(p);
    }

    AggPack ap;
    ap.Q = Qb; ap.KV = KVb; ap.R = Rb;
    ap.Wb = Wbeta + l * 2 * 192;
    ap.Hin = H;
    ap.lng = ln_g + l * 128;
    ap.lnb = ln_b + l * 128;
    ap.outHR = HN;
    ap.rowptr = rowptr;
    ap.colsrc = colsrc;
    agg_kernel<<<dim3(NN / 4, 2), dim3(256), 0, stream>>>(ap);

    FFPack fp;
    fp.HN = HN;
    fp.W1t = wt + WT_W1 + l * 2 * 16384;
    fp.W2t = wt + WT_W2 + l * 2 * 16384;
    fp.Wot = wt + WT_WO;
    fp.b1 = ff_b1 + l * 2 * 256;
    fp.b2 = ff_b2 + l * 2 * 64;
    fp.bout = b_out;
    fp.H  = H;
    fp.outbuf = (l == 1) ? out : nullptr;   // fuse output projection into last FF
    ff_fused<<<dim3(NN / 64, 2), dim3(256), 0, stream>>>(fp);
  }
}

// Round 8
// 325.751 us; speedup vs baseline: 1.0820x; 1.0820x over previous
//
#include <hip/hip_runtime.h>
#include <math.h>

#define NN 16384
#define EE 262144

typedef __bf16 v8bf __attribute__((ext_vector_type(8)));
typedef __bf16 v4bf __attribute__((ext_vector_type(4)));
typedef float  v4f  __attribute__((ext_vector_type(4)));
typedef float  v2f  __attribute__((ext_vector_type(2)));

// ---- workspace layout (units of 4-byte elements) ----
#define OFF_CNT     0                         // 2*NN ints
#define OFF_FILL    (2*NN)                    // 2*NN ints
#define OFF_ROWPTR  (4*NN)                    // 2*(NN+1) ints
#define OFF_COLSRC  98816                     // 2*EE ints (byte offsets)
#define OFF_H       623104                    // 2*NN*64 f32
#define OFF_HN      (OFF_H  + 2*NN*64)        // 2*NN*64 f32
#define OFF_Q       (OFF_HN + 2*NN*64)        // 2*NN*256 bf16 (512B rows, PERMUTED)
#define OFF_KV      (OFF_Q  + 2*NN*128)       // 2*NN rows of 512 B (K fp8 256B | V fp8 256B, PERMUTED)
#define OFF_R       (OFF_KV + 2*NN*128)       // 2*NN*64 f32
#define OFF_WT      (OFF_R  + 2*NN*64)        // transposed bf16 weights (ushort base)

// PERMUTED channel layout for Q/K/V buffers:
//   channel (head h, c = ct*16 + l16), ct in 0..3, l16 in 0..15
//   K/V fp8 byte at   h*64 + l16*4 + ct
//   Q bf16 ushort at  h*64 + l16*4 + ct
// agg's gather addresses (head*64 + c4*4) are numerically unchanged; only the
// interpretation (which channels a lane holds) changes: lane c4 owns {16i+c4}.

// bf16-element offsets inside WT area
#define WT_Q   0         // [4][256*64]
#define WT_K   65536
#define WT_V   131072
#define WT_S   196608    // [4][64*64]
#define WT_IN  212992    // [2][64*64]
#define WT_W1  221184    // [4][256*64]
#define WT_W2  286720    // [4][64*256]
#define WT_WO  352256    // [2][64*64]

__device__ __forceinline__ float blo(unsigned u) { return __uint_as_float(u << 16); }
__device__ __forceinline__ float bhi(unsigned u) { return __uint_as_float(u & 0xffff0000u); }
__device__ __forceinline__ unsigned short f2b(float f) {
  __bf16 h = (__bf16)f;
  return *(unsigned short*)&h;
}

// ======================= weight prep: f32 [K][N] -> bf16 [N][K] =======================
struct PrepDesc { const float* src; unsigned short* dst; int ksh; int total; };
struct PrepPack { PrepDesc d[28]; };

__global__ __launch_bounds__(256) void prep_kernel(PrepPack p) {
  PrepDesc g = p.d[blockIdx.y];
  int idx = blockIdx.x * 256 + threadIdx.x;
  if (idx >= g.total) return;
  int K = 1 << g.ksh;
  int n = idx >> g.ksh;
  int k = idx & (K - 1);
  int N = g.total >> g.ksh;
  g.dst[idx] = f2b(g.src[(size_t)k * N + n]);
}

// ======================= CSR build =======================
__global__ void count_kernel(const int* __restrict__ ei, int* __restrict__ cnt) {
  int idx = blockIdx.x * 256 + threadIdx.x;
  if (idx >= 2 * EE) return;
  int et = idx >> 18;
  int j  = idx & (EE - 1);
  int dst = ei[et * 2 * EE + EE + j];
  atomicAdd(&cnt[et * NN + dst], 1);
}

__global__ __launch_bounds__(1024) void scan_kernel(const int* __restrict__ cnt,
                                                    int* __restrict__ rowptr,
                                                    int* __restrict__ fill) {
  int et = blockIdx.x;
  const int* c = cnt + et * NN;
  __shared__ int sums[1024];
  int tid = threadIdx.x;
  int base = tid * 16;
  int loc[16];
  int s = 0;
#pragma unroll
  for (int i = 0; i < 16; ++i) { loc[i] = s; s += c[base + i]; }
  sums[tid] = s;
  __syncthreads();
  for (int off = 1; off < 1024; off <<= 1) {
    int v = 0;
    if (tid >= off) v = sums[tid - off];
    __syncthreads();
    if (tid >= off) sums[tid] += v;
    __syncthreads();
  }
  int ebase = (tid == 0) ? 0 : sums[tid - 1];
  int* rp = rowptr + et * (NN + 1);
  int* fl = fill + et * NN;
#pragma unroll
  for (int i = 0; i < 16; ++i) {
    rp[base + i] = ebase + loc[i];
    fl[base + i] = ebase + loc[i];
  }
  if (tid == 1023) rp[NN] = sums[1023];
}

// colsrc holds BYTE offset of the src node's KV row: (et*NN + src) * 512
__global__ void scatter_kernel(const int* __restrict__ ei, int* __restrict__ fill,
                               int* __restrict__ colsrc) {
  int idx = blockIdx.x * 256 + threadIdx.x;
  if (idx >= 2 * EE) return;
  int et = idx >> 18;
  int j  = idx & (EE - 1);
  int src = ei[et * 2 * EE + j];
  int dst = ei[et * 2 * EE + EE + j];
  int pos = atomicAdd(&fill[et * NN + dst], 1);
  colsrc[et * EE + pos] = (et * NN + src) << 9;
}

// ======================= bf16 MFMA tiled GEMM (R3 staging + packed permuted stores) =======================
// K=64 fixed. Bt is bf16 [Ncols][64]. otype: 0=f32 standard, 1=bf16 PERMUTED packed,
// 2=fp8 PERMUTED packed. Cld = C row stride in BYTES.
struct GemmDesc {
  const float *A, *bias, *bias2, *add;
  const unsigned short* Bt;
  char* C;
  int Ncols, Cld, ntiles, gelu, otype;
};
struct GemmPack { GemmDesc d[8]; int nd; };

#define LDA 72   // padded bf16 row stride

__global__ __launch_bounds__(256) void gemm_mfma(GemmPack p) {
  GemmDesc g = p.d[blockIdx.y];
  const int row0 = blockIdx.x * 128;
  const int tid = threadIdx.x;
  const int w = tid >> 6, lane = tid & 63;
  const int l16 = lane & 15, quad = lane >> 4;

  __shared__ __bf16 As[128 * LDA];
  __shared__ __bf16 Bs[64 * LDA];

  // stage A rows once (K=64)
#pragma unroll
  for (int it = 0; it < 8; ++it) {
    int fi = it * 256 + tid;
    int grow = fi >> 4;
    int kq = (fi & 15) << 2;
    float4 a = *(const float4*)(g.A + (size_t)(row0 + grow) * 64 + kq);
    v4bf c = { (__bf16)a.x, (__bf16)a.y, (__bf16)a.z, (__bf16)a.w };
    *(v4bf*)&As[grow * LDA + kq] = c;
  }

  const int brow = tid >> 2;          // 0..63 (B tile row)
  const int bko  = (tid & 3) << 4;    // k chunk: 0,16,32,48 (bf16 elems)

  for (int ct0 = 0; ct0 < g.ntiles; ++ct0) {
    const int col0 = ct0 * 64;
    __syncthreads();   // A ready (iter 0) / prior MFMA done reading Bs
    {
      const unsigned short* bp = g.Bt + (size_t)(col0 + brow) * 64 + bko;
      uint4 b0 = *(const uint4*)(bp);
      uint4 b1 = *(const uint4*)(bp + 8);
      *(uint4*)&Bs[brow * LDA + bko] = b0;
      *(uint4*)&Bs[brow * LDA + bko + 8] = b1;
    }
    __syncthreads();

    v4f acc[2][4];
#pragma unroll
    for (int rt = 0; rt < 2; ++rt)
#pragma unroll
      for (int ct = 0; ct < 4; ++ct)
#pragma unroll
        for (int r = 0; r < 4; ++r) acc[rt][ct][r] = 0.f;

#pragma unroll
    for (int ks = 0; ks < 2; ++ks) {
      v8bf a0 = *(v8bf*)&As[(w * 32 + l16) * LDA + ks * 32 + quad * 8];
      v8bf a1 = *(v8bf*)&As[(w * 32 + 16 + l16) * LDA + ks * 32 + quad * 8];
#pragma unroll
      for (int ct = 0; ct < 4; ++ct) {
        v8bf bb = *(v8bf*)&Bs[(ct * 16 + l16) * LDA + ks * 32 + quad * 8];
        acc[0][ct] = __builtin_amdgcn_mfma_f32_16x16x32_bf16(a0, bb, acc[0][ct], 0, 0, 0);
        acc[1][ct] = __builtin_amdgcn_mfma_f32_16x16x32_bf16(a1, bb, acc[1][ct], 0, 0, 0);
      }
    }

    float bias_c[4];
#pragma unroll
    for (int ct = 0; ct < 4; ++ct) {
      int col = col0 + ct * 16 + l16;
      float b = g.bias ? g.bias[col] : 0.f;
      if (g.bias2) b += g.bias2[col];
      bias_c[ct] = b;
    }
#pragma unroll
    for (int rt = 0; rt < 2; ++rt)
#pragma unroll
      for (int r = 0; r < 4; ++r) {
        size_t row = row0 + w * 32 + rt * 16 + quad * 4 + r;
        char* cp = g.C + row * (size_t)g.Cld;
        if (g.otype == 0) {
#pragma unroll
          for (int ct = 0; ct < 4; ++ct) {
            int col = col0 + ct * 16 + l16;
            float v = acc[rt][ct][r] + bias_c[ct];
            if (g.add) v += g.add[row * g.Ncols + col];
            if (g.gelu) v = 0.5f * v * (1.f + erff(v * 0.70710678118654752f));
            *(float*)(cp + col * 4) = v;
          }
        } else if (g.otype == 1) {
          // Q: 4 bf16 (ct=0..3) packed, permuted layout: ushort idx ct0*64 + l16*4 + ct
          ushort4 wq;
          wq.x = f2b(acc[rt][0][r] + bias_c[0]);
          wq.y = f2b(acc[rt][1][r] + bias_c[1]);
          wq.z = f2b(acc[rt][2][r] + bias_c[2]);
          wq.w = f2b(acc[rt][3][r] + bias_c[3]);
          *(ushort4*)(cp + col0 * 2 + l16 * 8) = wq;
        } else {
          // K/V fp8: 4 bytes (ct=0..3) packed, permuted layout: byte ct0*64 + l16*4 + ct
          unsigned wv = 0;
#pragma unroll
          for (int ct = 0; ct < 4; ++ct) {
            float v = acc[rt][ct][r] + bias_c[ct];
            unsigned pk = __builtin_amdgcn_cvt_pk_fp8_f32(v, v, 0, false);
            wv |= (pk & 0xffu) << (8 * ct);
          }
          *(unsigned*)(cp + col0 + l16 * 4) = wv;
        }
      }
  }
}

// ======================= fused FF (R3 version) + optional fused out-proj =======================
struct FFPack {
  const float *HN;
  const unsigned short *W1t, *W2t, *Wot;   // bf16 [n][k] transposed, per-type blocks
  const float *b1, *b2, *bout;
  float* H;
  float* outbuf;              // if non-null: write out = H@Wout+bout, skip H store
};

__global__ __launch_bounds__(256) void ff_fused(FFPack p) {
  const int t = blockIdx.y;
  const int row0 = blockIdx.x * 64;
  const int tid = threadIdx.x;
  const int w = tid >> 6, lane = tid & 63;
  const int l16 = lane & 15, quad = lane >> 4;

  const float* A  = p.HN + ((size_t)t * NN) * 64;
  const unsigned short* W1t = p.W1t + (size_t)t * 16384;  // [256][64]
  const unsigned short* W2t = p.W2t + (size_t)t * 16384;  // [64][256]
  const float* b1 = p.b1 + t * 256;
  const float* b2 = p.b2 + t * 64;

  __shared__ __bf16 As[64 * LDA];
  __shared__ __bf16 A2[64 * LDA];
  __shared__ __bf16 B1s[64 * LDA];
  __shared__ __bf16 B2s[64 * LDA];

#pragma unroll
  for (int it = 0; it < 4; ++it) {
    int fi = it * 256 + tid;
    int grow = fi >> 4;
    int kq = (fi & 15) << 2;
    float4 a = *(const float4*)(A + (size_t)(row0 + grow) * 64 + kq);
    v4bf c = { (__bf16)a.x, (__bf16)a.y, (__bf16)a.z, (__bf16)a.w };
    *(v4bf*)&As[grow * LDA + kq] = c;
  }

  const int brow = tid >> 2;          // 0..63
  const int bko  = (tid & 3) << 4;    // 0,16,32,48

  v4f acc2[4];
#pragma unroll
  for (int ct = 0; ct < 4; ++ct)
#pragma unroll
    for (int r = 0; r < 4; ++r) acc2[ct][r] = 0.f;

  for (int c1 = 0; c1 < 4; ++c1) {
    {
      const unsigned short* bp1 = W1t + (size_t)(c1 * 64 + brow) * 64 + bko;
      uint4 u0 = *(const uint4*)(bp1);
      uint4 u1 = *(const uint4*)(bp1 + 8);
      *(uint4*)&B1s[brow * LDA + bko] = u0;
      *(uint4*)&B1s[brow * LDA + bko + 8] = u1;
      const unsigned short* bp2 = W2t + (size_t)brow * 256 + c1 * 64 + bko;
      uint4 u2 = *(const uint4*)(bp2);
      uint4 u3 = *(const uint4*)(bp2 + 8);
      *(uint4*)&B2s[brow * LDA + bko] = u2;
      *(uint4*)&B2s[brow * LDA + bko + 8] = u3;
    }
    __syncthreads();

    v4f acc1[4];
#pragma unroll
    for (int ct = 0; ct < 4; ++ct)
#pragma unroll
      for (int r = 0; r < 4; ++r) acc1[ct][r] = 0.f;
#pragma unroll
    for (int ks = 0; ks < 2; ++ks) {
      v8bf a = *(v8bf*)&As[(w * 16 + l16) * LDA + ks * 32 + quad * 8];
#pragma unroll
      for (int ct = 0; ct < 4; ++ct) {
        v8bf bb = *(v8bf*)&B1s[(ct * 16 + l16) * LDA + ks * 32 + quad * 8];
        acc1[ct] = __builtin_amdgcn_mfma_f32_16x16x32_bf16(a, bb, acc1[ct], 0, 0, 0);
      }
    }
#pragma unroll
    for (int ct = 0; ct < 4; ++ct) {
      float bb = b1[c1 * 64 + ct * 16 + l16];
#pragma unroll
      for (int r = 0; r < 4; ++r) {
        float v = acc1[ct][r] + bb;
        v = 0.5f * v * (1.f + erff(v * 0.70710678118654752f));
        A2[(w * 16 + quad * 4 + r) * LDA + ct * 16 + l16] = (__bf16)v;
      }
    }
    // wave-private 16-row slice: compiler-inserted lgkmcnt orders the RAW
#pragma unroll
    for (int ks = 0; ks < 2; ++ks) {
      v8bf a = *(v8bf*)&A2[(w * 16 + l16) * LDA + ks * 32 + quad * 8];
#pragma unroll
      for (int ct = 0; ct < 4; ++ct) {
        v8bf bb = *(v8bf*)&B2s[(ct * 16 + l16) * LDA + ks * 32 + quad * 8];
        acc2[ct] = __builtin_amdgcn_mfma_f32_16x16x32_bf16(a, bb, acc2[ct], 0, 0, 0);
      }
    }
    __syncthreads();
  }

  if (!p.outbuf) {
    // standard epilogue: H = hr + acc2 + b2
#pragma unroll
    for (int ct = 0; ct < 4; ++ct) {
      int col = ct * 16 + l16;
      float bb = b2[col];
#pragma unroll
      for (int r = 0; r < 4; ++r) {
        size_t row = (size_t)t * NN + row0 + w * 16 + quad * 4 + r;
        float v = acc2[ct][r] + bb + p.HN[row * 64 + col];
        p.H[row * 64 + col] = v;
      }
    }
    return;
  }

  // ---- fused output projection (last layer): out = (hr+ff) @ Wout + bout ----
#pragma unroll
  for (int ct = 0; ct < 4; ++ct) {
    int col = ct * 16 + l16;
    float bb = b2[col];
#pragma unroll
    for (int r = 0; r < 4; ++r) {
      int lrow = w * 16 + quad * 4 + r;
      size_t row = (size_t)t * NN + row0 + lrow;
      float v = acc2[ct][r] + bb + p.HN[row * 64 + col];
      A2[lrow * LDA + col] = (__bf16)v;
    }
  }
  {
    const unsigned short* Wot = p.Wot + (size_t)t * 4096;  // [64][64]
    const unsigned short* bp = Wot + (size_t)brow * 64 + bko;
    uint4 u0 = *(const uint4*)(bp);
    uint4 u1 = *(const uint4*)(bp + 8);
    *(uint4*)&B1s[brow * LDA + bko] = u0;
    *(uint4*)&B1s[brow * LDA + bko + 8] = u1;
  }
  __syncthreads();

  v4f acc3[4];
#pragma unroll
  for (int ct = 0; ct < 4; ++ct)
#pragma unroll
    for (int r = 0; r < 4; ++r) acc3[ct][r] = 0.f;
#pragma unroll
  for (int ks = 0; ks < 2; ++ks) {
    v8bf a = *(v8bf*)&A2[(w * 16 + l16) * LDA + ks * 32 + quad * 8];
#pragma unroll
    for (int ct = 0; ct < 4; ++ct) {
      v8bf bb = *(v8bf*)&B1s[(ct * 16 + l16) * LDA + ks * 32 + quad * 8];
      acc3[ct] = __builtin_amdgcn_mfma_f32_16x16x32_bf16(a, bb, acc3[ct], 0, 0, 0);
    }
  }
  const float* bo = p.bout + t * 64;
#pragma unroll
  for (int ct = 0; ct < 4; ++ct) {
    int col = ct * 16 + l16;
    float bb = bo[col];
#pragma unroll
    for (int r = 0; r < 4; ++r) {
      size_t row = (size_t)t * NN + row0 + w * 16 + quad * 4 + r;
      p.outbuf[row * 64 + col] = acc3[ct][r] + bb;
    }
  }
}

// ======================= edge aggregation + beta + LN (permuted channel layout) =======================
// grid.y = edge type; one wave / dst node; lane = head*16 + c4.
// Gather loop identical to R3 (addresses unchanged); lane c4 now holds channels
// {16*i + c4 : i=0..3} instead of {4*c4..4*c4+3}. Epilogue uses stride-16 access.
struct AggPack {
  const unsigned short *Q;   // [2*NN][256] bf16 permuted (dst-type indexed)
  const char *KV;            // [2*NN] rows of 512 B permuted (src-type indexed)
  const float *R;            // [2*NN][64]
  const float *Wb;
  const float *Hin;
  const float *lng, *lnb;
  float* outHR;
  const int *rowptr;
  const int *colsrc;         // byte offsets
};

__global__ __launch_bounds__(256) void agg_kernel(AggPack p) {
  const int et = blockIdx.y, d = 1 - et;
  int wid = __builtin_amdgcn_readfirstlane(threadIdx.x >> 6);
  int lane = threadIdx.x & 63;
  int node = blockIdx.x * 4 + wid;
  int c4 = lane & 15;
  int cb = ((lane >> 4) << 6) + (c4 << 2);   // byte/elem offset: head*64 + c4*4 (same as R3)

  const int* rp = p.rowptr + et * (NN + 1);
  const int* cs = p.colsrc + et * EE;
  int start = rp[node], end = rp[node + 1];
  int len = end - start;
  int gnode = d * NN + node;

  uint2 qw = *(const uint2*)(p.Q + ((size_t)gnode << 8) + cb);
  float q0 = blo(qw.x) * 0.125f, q1 = bhi(qw.x) * 0.125f;
  float q2 = blo(qw.y) * 0.125f, q3 = bhi(qw.y) * 0.125f;

  int b[5];
#pragma unroll
  for (int i = 0; i <= 4; ++i) b[i] = start + ((len * i) >> 2);
  float dsum[4] = {0.f, 0.f, 0.f, 0.f};
  float acc[4][4];
#pragma unroll
  for (int s4 = 0; s4 < 4; ++s4)
#pragma unroll
    for (int c = 0; c < 4; ++c) acc[s4][c] = 0.f;

  int maxn = (len + 3) >> 2;
  int last = end - 1;
  for (int it = 0; it < maxn; ++it) {
#pragma unroll
    for (int s4 = 0; s4 < 4; ++s4) {
      int j = b[s4] + it;
      bool act = j < b[s4 + 1];
      int jc = act ? j : last;
      int off = cs[jc];                      // KV row byte offset
      const char* rowp = p.KV + off;
      unsigned kw = *(const unsigned*)(rowp + cb);          // 4 fp8 K vals (perm)
      unsigned vw = *(const unsigned*)(rowp + 256 + cb);    // 4 fp8 V vals (perm)
      v2f kl = __builtin_amdgcn_cvt_pk_f32_fp8((int)kw, false);
      v2f kh = __builtin_amdgcn_cvt_pk_f32_fp8((int)kw, true);
      float pd = q0 * kl[0] + q1 * kl[1] + q2 * kh[0] + q3 * kh[1];
      pd += __shfl_xor(pd, 1);
      pd += __shfl_xor(pd, 2);
      pd += __shfl_xor(pd, 4);
      pd += __shfl_xor(pd, 8);
      float wgt = act ? __expf(pd) : 0.f;
      v2f vl = __builtin_amdgcn_cvt_pk_f32_fp8((int)vw, false);
      v2f vh = __builtin_amdgcn_cvt_pk_f32_fp8((int)vw, true);
      dsum[s4] += wgt;
      acc[s4][0] += wgt * vl[0];
      acc[s4][1] += wgt * vl[1];
      acc[s4][2] += wgt * vh[0];
      acc[s4][3] += wgt * vh[1];
    }
  }
  // exact stream merge; o_[i] = channel (16*i + c4) within head
  float dn = (dsum[0] + dsum[1]) + (dsum[2] + dsum[3]);
  float o_[4];
#pragma unroll
  for (int i = 0; i < 4; ++i)
    o_[i] = (acc[0][i] + acc[1][i]) + (acc[2][i] + acc[3][i]);

  float inv = (len > 0) ? (0.25f / dn) : 0.f;
#pragma unroll
  for (int i = 0; i < 4; ++i) {
    float a = o_[i] * inv;
    a += __shfl_xor(a, 16);   // head mean (same channel-within-head across heads)
    a += __shfl_xor(a, 32);
    o_[i] = a;
  }

  // epilogue: lane c4 owns output channels 16*i + c4
  const float* wb = p.Wb + et * 192;
  float rr[4], hh[4];
#pragma unroll
  for (int i = 0; i < 4; ++i) {
    int c = i * 16 + c4;
    rr[i] = p.R[(size_t)gnode * 64 + c];
    hh[i] = p.Hin[(size_t)gnode * 64 + c];
  }
  float part = 0.f;
#pragma unroll
  for (int i = 0; i < 4; ++i) {
    int c = i * 16 + c4;
    part += o_[i] * wb[c] + rr[i] * wb[64 + c] + (o_[i] - rr[i]) * wb[128 + c];
  }
  part += __shfl_xor(part, 1);
  part += __shfl_xor(part, 2);
  part += __shfl_xor(part, 4);
  part += __shfl_xor(part, 8);
  float beta = 1.f / (1.f + __expf(-part));

  float y[4];
  float sa = 0.f, sb = 0.f;
#pragma unroll
  for (int i = 0; i < 4; ++i) {
    float v = hh[i] + beta * rr[i] + (1.f - beta) * o_[i];
    y[i] = v;
    sa += v;
    sb += v * v;
  }
  sa += __shfl_xor(sa, 1); sb += __shfl_xor(sb, 1);
  sa += __shfl_xor(sa, 2); sb += __shfl_xor(sb, 2);
  sa += __shfl_xor(sa, 4); sb += __shfl_xor(sb, 4);
  sa += __shfl_xor(sa, 8); sb += __shfl_xor(sb, 8);
  float mu = sa * (1.f / 64.f);
  float var = sb * (1.f / 64.f) - mu * mu;
  float rs = rsqrtf(var + 1e-5f);
  if (lane < 16) {
    const float* lng = p.lng + d * 64;
    const float* lnb = p.lnb + d * 64;
#pragma unroll
    for (int i = 0; i < 4; ++i) {
      int c = i * 16 + c4;
      p.outHR[(size_t)gnode * 64 + c] = (y[i] - mu) * rs * lng[c] + lnb[c];
    }
  }
}

// ======================= host =======================
static void add_desc(GemmPack& p, const float* A, const unsigned short* Bt,
                     const float* bias, const float* bias2, const float* add,
                     void* C, int Nc, int Cld, int gelu, int otype) {
  GemmDesc& g = p.d[p.nd++];
  g.A = A; g.Bt = Bt; g.bias = bias; g.bias2 = bias2; g.add = add; g.C = (char*)C;
  g.Ncols = Nc; g.Cld = Cld; g.ntiles = Nc / 64;
  g.gelu = gelu; g.otype = otype;
}

extern "C" void kernel_launch(void* const* d_in, const int* in_sizes, int n_in,
                              void* d_out, int out_size, void* d_ws, size_t ws_size,
                              hipStream_t stream) {
  const float* x        = (const float*)d_in[0];
  const int*   ei       = (const int*)d_in[1];
  const float* W_in     = (const float*)d_in[2];
  const float* b_in     = (const float*)d_in[3];
  const float* type_emb = (const float*)d_in[4];
  const float* pos      = (const float*)d_in[5];
  const float* Wq       = (const float*)d_in[6];
  const float* bq       = (const float*)d_in[7];
  const float* Wk       = (const float*)d_in[8];
  const float* bk       = (const float*)d_in[9];
  const float* Wv       = (const float*)d_in[10];
  const float* bv       = (const float*)d_in[11];
  const float* Wskip    = (const float*)d_in[12];
  const float* bskip    = (const float*)d_in[13];
  const float* Wbeta    = (const float*)d_in[14];
  const float* ln_g     = (const float*)d_in[15];
  const float* ln_b     = (const float*)d_in[16];
  const float* ff_W1    = (const float*)d_in[17];
  const float* ff_b1    = (const float*)d_in[18];
  const float* ff_W2    = (const float*)d_in[19];
  const float* ff_b2    = (const float*)d_in[20];
  const float* W_out    = (const float*)d_in[21];
  const float* b_out    = (const float*)d_in[22];
  float* out = (float*)d_out;

  int*   wsi = (int*)d_ws;
  float* wsf = (float*)d_ws;
  int* cnt    = wsi + OFF_CNT;
  int* fill   = wsi + OFF_FILL;
  int* rowptr = wsi + OFF_ROWPTR;
  int* colsrc = wsi + OFF_COLSRC;
  float* H  = wsf + OFF_H;
  float* HN = wsf + OFF_HN;
  unsigned short* Qb = (unsigned short*)(wsf + OFF_Q);
  char* KVb = (char*)(wsf + OFF_KV);
  float* Rb = wsf + OFF_R;
  unsigned short* wt = (unsigned short*)(wsf + OFF_WT);

  // ---- weight prep (transpose + bf16), once per launch ----
  {
    PrepPack pp{};
    int nd = 0;
    for (int we = 0; we < 4; ++we) {
      pp.d[nd++] = { Wq + (size_t)we * 16384, wt + WT_Q + we * 16384, 6, 16384 };
      pp.d[nd++] = { Wk + (size_t)we * 16384, wt + WT_K + we * 16384, 6, 16384 };
      pp.d[nd++] = { Wv + (size_t)we * 16384, wt + WT_V + we * 16384, 6, 16384 };
      pp.d[nd++] = { Wskip + (size_t)we * 4096, wt + WT_S + we * 4096, 6, 4096 };
      pp.d[nd++] = { ff_W1 + (size_t)we * 16384, wt + WT_W1 + we * 16384, 6, 16384 };
      pp.d[nd++] = { ff_W2 + (size_t)we * 16384, wt + WT_W2 + we * 16384, 8, 16384 };
    }
    for (int t = 0; t < 2; ++t) {
      pp.d[nd++] = { W_in + (size_t)t * 4096, wt + WT_IN + t * 4096, 6, 4096 };
      pp.d[nd++] = { W_out + (size_t)t * 4096, wt + WT_WO + t * 4096, 6, 4096 };
    }
    prep_kernel<<<dim3(64, nd), dim3(256), 0, stream>>>(pp);
  }

  // ---- CSR build ----
  hipMemsetAsync(cnt, 0, 2 * NN * sizeof(int), stream);
  count_kernel<<<dim3(2 * EE / 256), dim3(256), 0, stream>>>(ei, cnt);
  scan_kernel<<<dim3(2), dim3(1024), 0, stream>>>(cnt, rowptr, fill);
  scatter_kernel<<<dim3(2 * EE / 256), dim3(256), 0, stream>>>(ei, fill, colsrc);

  // ---- input projection ----
  {
    GemmPack p{};
    for (int t = 0; t < 2; ++t)
      add_desc(p, x + (size_t)t * NN * 64, wt + WT_IN + t * 4096,
               b_in + t * 64, type_emb + t * 64, pos + (size_t)t * NN * 64,
               H + (size_t)t * NN * 64, 64, 256, 0, 0);
    gemm_mfma<<<dim3(128, p.nd), dim3(256), 0, stream>>>(p);
  }

  for (int l = 0; l < 2; ++l) {
    // one batched GEMM for both edge types: q,k,v,skip x 2
    {
      GemmPack p{};
      for (int et = 0; et < 2; ++et) {
        int s = et, d = 1 - et;
        int we = l * 2 + et;
        const float* hs = H + (size_t)s * NN * 64;
        const float* hd = H + (size_t)d * NN * 64;
        add_desc(p, hd, wt + WT_Q + we * 16384, bq + we * 256,
                 nullptr, nullptr, (char*)Qb + (size_t)d * NN * 512, 256, 512, 0, 1);
        add_desc(p, hs, wt + WT_K + we * 16384, bk + we * 256,
                 nullptr, nullptr, KVb + (size_t)s * NN * 512, 256, 512, 0, 2);
        add_desc(p, hs, wt + WT_V + we * 16384, bv + we * 256,
                 nullptr, nullptr, KVb + (size_t)s * NN * 512 + 256, 256, 512, 0, 2);
        add_desc(p, hd, wt + WT_S + we * 4096, bskip + we * 64,
                 nullptr, nullptr, Rb + (size_t)d * NN * 64, 64, 256, 0, 0);
      }
      gemm_mfma<<<dim3(128, p.nd), dim3(256), 0, stream>>>(p);
    }

    AggPack ap;
    ap.Q = Qb; ap.KV = KVb; ap.R = Rb;
    ap.Wb = Wbeta + l * 2 * 192;
    ap.Hin = H;
    ap.lng = ln_g + l * 128;
    ap.lnb = ln_b + l * 128;
    ap.outHR = HN;
    ap.rowptr = rowptr;
    ap.colsrc = colsrc;
    agg_kernel<<<dim3(NN / 4, 2), dim3(256), 0, stream>>>(ap);

    FFPack fp;
    fp.HN = HN;
    fp.W1t = wt + WT_W1 + l * 2 * 16384;
    fp.W2t = wt + WT_W2 + l * 2 * 16384;
    fp.Wot = wt + WT_WO;
    fp.b1 = ff_b1 + l * 2 * 256;
    fp.b2 = ff_b2 + l * 2 * 64;
    fp.bout = b_out;
    fp.H  = H;
    fp.outbuf = (l == 1) ? out : nullptr;   // fuse output projection into last FF
    ff_fused<<<dim3(NN / 64, 2), dim3(256), 0, stream>>>(fp);
  }
}

// Round 9
// 320.263 us; speedup vs baseline: 1.1005x; 1.0171x over previous
//
#include <hip/hip_runtime.h>
#include <math.h>

#define NN 16384
#define EE 262144

typedef __bf16 v8bf __attribute__((ext_vector_type(8)));
typedef __bf16 v4bf __attribute__((ext_vector_type(4)));
typedef float  v4f  __attribute__((ext_vector_type(4)));
typedef float  v2f  __attribute__((ext_vector_type(2)));

// ---- workspace layout (units of 4-byte elements) ----
#define OFF_CNT     0                         // 2*NN ints
#define OFF_FILL    (2*NN)                    // 2*NN ints
#define OFF_ROWPTR  (4*NN)                    // 2*(NN+1) ints
#define OFF_COLSRC  98816                     // 2*EE ints (byte offsets)
#define OFF_H       623104                    // 2*NN*64 f32 (PERMUTED hidden axis)
#define OFF_HN      (OFF_H  + 2*NN*64)        // 2*NN*64 f32 (PERMUTED)
#define OFF_Q       (OFF_HN + 2*NN*64)        // 2*NN*256 bf16 (512B rows, PERMUTED qkv axis)
#define OFF_KV      (OFF_Q  + 2*NN*128)       // 2*NN rows 512 B (K fp8 | V fp8, PERMUTED)
#define OFF_R       (OFF_KV + 2*NN*128)       // 2*NN*64 f32 (PERMUTED)
#define OFF_WT      (OFF_R  + 2*NN*64)        // transposed bf16 weights (ushort base)
#define OFF_WBP     (OFF_WT + 180224)         // 768 f32: permuted Wbeta
#define OFF_LNG     (OFF_WBP + 768)           // 256 f32: permuted ln_g
#define OFF_LNB     (OFF_LNG + 256)           // 256 f32: permuted ln_b

// Channel permutation on any 64-wide axis: storage position P(c) = 4*(c&15) + (c>>4).
// Lane l16 of a 16-lane group owns channels {16i + l16 : i=0..3}, stored contiguously
// at positions 4*l16..4*l16+3 -> every epilogue load/store is a float4.
// Inverse: position k holds channel invP(k) = 16*(k&3) + (k>>2).

// bf16-element offsets inside WT area
#define WT_Q   0         // [4][256*64]
#define WT_K   65536
#define WT_V   131072
#define WT_S   196608    // [4][64*64]
#define WT_IN  212992    // [2][64*64]
#define WT_W1  221184    // [4][256*64]
#define WT_W2  286720    // [4][64*256]
#define WT_WO  352256    // [2][64*64]

__device__ __forceinline__ float blo(unsigned u) { return __uint_as_float(u << 16); }
__device__ __forceinline__ float bhi(unsigned u) { return __uint_as_float(u & 0xffff0000u); }
__device__ __forceinline__ unsigned short f2b(float f) {
  __bf16 h = (__bf16)f;
  return *(unsigned short*)&h;
}

// ======================= weight prep: f32 [K][N] -> bf16 [N][K(perm)] =======================
// kperm: if set (K=64 hidden axis), position k holds channel invP(k).
struct PrepDesc { const float* src; unsigned short* dst; int ksh; int total; int kperm; };
struct PrepPack { PrepDesc d[28]; };

__global__ __launch_bounds__(256) void prep_kernel(PrepPack p) {
  PrepDesc g = p.d[blockIdx.y];
  int idx = blockIdx.x * 256 + threadIdx.x;
  if (idx >= g.total) return;
  int K = 1 << g.ksh;
  int n = idx >> g.ksh;
  int k = idx & (K - 1);
  int N = g.total >> g.ksh;
  int kk = g.kperm ? (16 * (k & 3) + (k >> 2)) : k;
  g.dst[idx] = f2b(g.src[(size_t)kk * N + n]);
}

// f32 64-block channel permute: dst[b*64 + P(c)] = src[b*64 + c]
struct PermDesc { const float* src; float* dst; int total; };
struct PermPack { PermDesc d[3]; };

__global__ __launch_bounds__(256) void perm_kernel(PermPack p) {
  PermDesc g = p.d[blockIdx.y];
  int idx = blockIdx.x * 256 + threadIdx.x;
  if (idx >= g.total) return;
  int c = idx & 63;
  g.dst[(idx & ~63) + ((c & 15) << 2) + (c >> 4)] = g.src[idx];
}

// ======================= CSR build =======================
__global__ void count_kernel(const int* __restrict__ ei, int* __restrict__ cnt) {
  int idx = blockIdx.x * 256 + threadIdx.x;
  if (idx >= 2 * EE) return;
  int et = idx >> 18;
  int j  = idx & (EE - 1);
  int dst = ei[et * 2 * EE + EE + j];
  atomicAdd(&cnt[et * NN + dst], 1);
}

__global__ __launch_bounds__(1024) void scan_kernel(const int* __restrict__ cnt,
                                                    int* __restrict__ rowptr,
                                                    int* __restrict__ fill) {
  int et = blockIdx.x;
  const int* c = cnt + et * NN;
  __shared__ int sums[1024];
  int tid = threadIdx.x;
  int base = tid * 16;
  int loc[16];
  int s = 0;
#pragma unroll
  for (int i = 0; i < 16; ++i) { loc[i] = s; s += c[base + i]; }
  sums[tid] = s;
  __syncthreads();
  for (int off = 1; off < 1024; off <<= 1) {
    int v = 0;
    if (tid >= off) v = sums[tid - off];
    __syncthreads();
    if (tid >= off) sums[tid] += v;
    __syncthreads();
  }
  int ebase = (tid == 0) ? 0 : sums[tid - 1];
  int* rp = rowptr + et * (NN + 1);
  int* fl = fill + et * NN;
#pragma unroll
  for (int i = 0; i < 16; ++i) {
    rp[base + i] = ebase + loc[i];
    fl[base + i] = ebase + loc[i];
  }
  if (tid == 1023) rp[NN] = sums[1023];
}

// colsrc holds BYTE offset of the src node's KV row: (et*NN + src) * 512
__global__ void scatter_kernel(const int* __restrict__ ei, int* __restrict__ fill,
                               int* __restrict__ colsrc) {
  int idx = blockIdx.x * 256 + threadIdx.x;
  if (idx >= 2 * EE) return;
  int et = idx >> 18;
  int j  = idx & (EE - 1);
  int src = ei[et * 2 * EE + j];
  int dst = ei[et * 2 * EE + EE + j];
  int pos = atomicAdd(&fill[et * NN + dst], 1);
  colsrc[et * EE + pos] = (et * NN + src) << 9;
}

// ======================= bf16 MFMA tiled GEMM (R3 staging + packed permuted stores) =======================
// K=64 fixed. Bt is bf16 [Ncols][64]. otype: 0=f32 PERMUTED packed (float4),
// 1=bf16 PERMUTED packed (Q), 2=fp8 PERMUTED packed (K/V). Cld in BYTES.
struct GemmDesc {
  const float *A, *bias, *bias2, *add;
  const unsigned short* Bt;
  char* C;
  int Ncols, Cld, ntiles, gelu, otype;
};
struct GemmPack { GemmDesc d[8]; int nd; };

#define LDA 72   // padded bf16 row stride

__global__ __launch_bounds__(256) void gemm_mfma(GemmPack p) {
  GemmDesc g = p.d[blockIdx.y];
  const int row0 = blockIdx.x * 128;
  const int tid = threadIdx.x;
  const int w = tid >> 6, lane = tid & 63;
  const int l16 = lane & 15, quad = lane >> 4;

  __shared__ __bf16 As[128 * LDA];
  __shared__ __bf16 Bs[64 * LDA];

  // stage A rows once (K=64)
#pragma unroll
  for (int it = 0; it < 8; ++it) {
    int fi = it * 256 + tid;
    int grow = fi >> 4;
    int kq = (fi & 15) << 2;
    float4 a = *(const float4*)(g.A + (size_t)(row0 + grow) * 64 + kq);
    v4bf c = { (__bf16)a.x, (__bf16)a.y, (__bf16)a.z, (__bf16)a.w };
    *(v4bf*)&As[grow * LDA + kq] = c;
  }

  const int brow = tid >> 2;          // 0..63 (B tile row)
  const int bko  = (tid & 3) << 4;    // k chunk: 0,16,32,48 (bf16 elems)

  for (int ct0 = 0; ct0 < g.ntiles; ++ct0) {
    const int col0 = ct0 * 64;
    __syncthreads();   // A ready (iter 0) / prior MFMA done reading Bs
    {
      const unsigned short* bp = g.Bt + (size_t)(col0 + brow) * 64 + bko;
      uint4 b0 = *(const uint4*)(bp);
      uint4 b1 = *(const uint4*)(bp + 8);
      *(uint4*)&Bs[brow * LDA + bko] = b0;
      *(uint4*)&Bs[brow * LDA + bko + 8] = b1;
    }
    __syncthreads();

    v4f acc[2][4];
#pragma unroll
    for (int rt = 0; rt < 2; ++rt)
#pragma unroll
      for (int ct = 0; ct < 4; ++ct)
#pragma unroll
        for (int r = 0; r < 4; ++r) acc[rt][ct][r] = 0.f;

#pragma unroll
    for (int ks = 0; ks < 2; ++ks) {
      v8bf a0 = *(v8bf*)&As[(w * 32 + l16) * LDA + ks * 32 + quad * 8];
      v8bf a1 = *(v8bf*)&As[(w * 32 + 16 + l16) * LDA + ks * 32 + quad * 8];
#pragma unroll
      for (int ct = 0; ct < 4; ++ct) {
        v8bf bb = *(v8bf*)&Bs[(ct * 16 + l16) * LDA + ks * 32 + quad * 8];
        acc[0][ct] = __builtin_amdgcn_mfma_f32_16x16x32_bf16(a0, bb, acc[0][ct], 0, 0, 0);
        acc[1][ct] = __builtin_amdgcn_mfma_f32_16x16x32_bf16(a1, bb, acc[1][ct], 0, 0, 0);
      }
    }

    float bias_c[4];
#pragma unroll
    for (int ct = 0; ct < 4; ++ct) {
      int col = col0 + ct * 16 + l16;
      float b = g.bias ? g.bias[col] : 0.f;
      if (g.bias2) b += g.bias2[col];
      bias_c[ct] = b;
    }
#pragma unroll
    for (int rt = 0; rt < 2; ++rt)
#pragma unroll
      for (int r = 0; r < 4; ++r) {
        size_t row = row0 + w * 32 + rt * 16 + quad * 4 + r;
        char* cp = g.C + row * (size_t)g.Cld;
        if (g.otype == 0) {
          // f32 permuted packed: position col0 + l16*4 + ct <- channel col0 + ct*16 + l16
          float vv[4];
#pragma unroll
          for (int ct = 0; ct < 4; ++ct) {
            int col = col0 + ct * 16 + l16;
            float v = acc[rt][ct][r] + bias_c[ct];
            if (g.add) v += g.add[row * g.Ncols + col];
            if (g.gelu) v = 0.5f * v * (1.f + erff(v * 0.70710678118654752f));
            vv[ct] = v;
          }
          float4 w4 = { vv[0], vv[1], vv[2], vv[3] };
          *(float4*)(cp + col0 * 4 + l16 * 16) = w4;
        } else if (g.otype == 1) {
          ushort4 wq;
          wq.x = f2b(acc[rt][0][r] + bias_c[0]);
          wq.y = f2b(acc[rt][1][r] + bias_c[1]);
          wq.z = f2b(acc[rt][2][r] + bias_c[2]);
          wq.w = f2b(acc[rt][3][r] + bias_c[3]);
          *(ushort4*)(cp + col0 * 2 + l16 * 8) = wq;
        } else {
          unsigned wv = 0;
#pragma unroll
          for (int ct = 0; ct < 4; ++ct) {
            float v = acc[rt][ct][r] + bias_c[ct];
            unsigned pk = __builtin_amdgcn_cvt_pk_fp8_f32(v, v, 0, false);
            wv |= (pk & 0xffu) << (8 * ct);
          }
          *(unsigned*)(cp + col0 + l16 * 4) = wv;
        }
      }
  }
}

// ======================= fused FF (permuted HN/H) + optional fused out-proj =======================
struct FFPack {
  const float *HN;
  const unsigned short *W1t, *W2t, *Wot;   // W1t k-permuted; W2t/Wot standard
  const float *b1, *b2, *bout;
  float* H;
  float* outbuf;              // if non-null: write out = H@Wout+bout, skip H store
};

__global__ __launch_bounds__(256) void ff_fused(FFPack p) {
  const int t = blockIdx.y;
  const int row0 = blockIdx.x * 64;
  const int tid = threadIdx.x;
  const int w = tid >> 6, lane = tid & 63;
  const int l16 = lane & 15, quad = lane >> 4;

  const float* A  = p.HN + ((size_t)t * NN) * 64;
  const unsigned short* W1t = p.W1t + (size_t)t * 16384;  // [256][64 perm]
  const unsigned short* W2t = p.W2t + (size_t)t * 16384;  // [64][256]
  const float* b1 = p.b1 + t * 256;
  const float* b2 = p.b2 + t * 64;

  __shared__ __bf16 As[64 * LDA];
  __shared__ __bf16 A2[64 * LDA];
  __shared__ __bf16 B1s[64 * LDA];
  __shared__ __bf16 B2s[64 * LDA];

#pragma unroll
  for (int it = 0; it < 4; ++it) {
    int fi = it * 256 + tid;
    int grow = fi >> 4;
    int kq = (fi & 15) << 2;
    float4 a = *(const float4*)(A + (size_t)(row0 + grow) * 64 + kq);
    v4bf c = { (__bf16)a.x, (__bf16)a.y, (__bf16)a.z, (__bf16)a.w };
    *(v4bf*)&As[grow * LDA + kq] = c;
  }

  const int brow = tid >> 2;          // 0..63
  const int bko  = (tid & 3) << 4;    // 0,16,32,48

  v4f acc2[4];
#pragma unroll
  for (int ct = 0; ct < 4; ++ct)
#pragma unroll
    for (int r = 0; r < 4; ++r) acc2[ct][r] = 0.f;

  for (int c1 = 0; c1 < 4; ++c1) {
    {
      const unsigned short* bp1 = W1t + (size_t)(c1 * 64 + brow) * 64 + bko;
      uint4 u0 = *(const uint4*)(bp1);
      uint4 u1 = *(const uint4*)(bp1 + 8);
      *(uint4*)&B1s[brow * LDA + bko] = u0;
      *(uint4*)&B1s[brow * LDA + bko + 8] = u1;
      const unsigned short* bp2 = W2t + (size_t)brow * 256 + c1 * 64 + bko;
      uint4 u2 = *(const uint4*)(bp2);
      uint4 u3 = *(const uint4*)(bp2 + 8);
      *(uint4*)&B2s[brow * LDA + bko] = u2;
      *(uint4*)&B2s[brow * LDA + bko + 8] = u3;
    }
    __syncthreads();

    v4f acc1[4];
#pragma unroll
    for (int ct = 0; ct < 4; ++ct)
#pragma unroll
      for (int r = 0; r < 4; ++r) acc1[ct][r] = 0.f;
#pragma unroll
    for (int ks = 0; ks < 2; ++ks) {
      v8bf a = *(v8bf*)&As[(w * 16 + l16) * LDA + ks * 32 + quad * 8];
#pragma unroll
      for (int ct = 0; ct < 4; ++ct) {
        v8bf bb = *(v8bf*)&B1s[(ct * 16 + l16) * LDA + ks * 32 + quad * 8];
        acc1[ct] = __builtin_amdgcn_mfma_f32_16x16x32_bf16(a, bb, acc1[ct], 0, 0, 0);
      }
    }
#pragma unroll
    for (int ct = 0; ct < 4; ++ct) {
      float bb = b1[c1 * 64 + ct * 16 + l16];
#pragma unroll
      for (int r = 0; r < 4; ++r) {
        float v = acc1[ct][r] + bb;
        v = 0.5f * v * (1.f + erff(v * 0.70710678118654752f));
        A2[(w * 16 + quad * 4 + r) * LDA + ct * 16 + l16] = (__bf16)v;
      }
    }
    // wave-private 16-row slice: compiler-inserted lgkmcnt orders the RAW
#pragma unroll
    for (int ks = 0; ks < 2; ++ks) {
      v8bf a = *(v8bf*)&A2[(w * 16 + l16) * LDA + ks * 32 + quad * 8];
#pragma unroll
      for (int ct = 0; ct < 4; ++ct) {
        v8bf bb = *(v8bf*)&B2s[(ct * 16 + l16) * LDA + ks * 32 + quad * 8];
        acc2[ct] = __builtin_amdgcn_mfma_f32_16x16x32_bf16(a, bb, acc2[ct], 0, 0, 0);
      }
    }
    __syncthreads();
  }

  float b2c[4];
#pragma unroll
  for (int ct = 0; ct < 4; ++ct) b2c[ct] = b2[ct * 16 + l16];

  if (!p.outbuf) {
    // H = hr + acc2 + b2, permuted storage: position 4*l16+ct <- channel ct*16+l16
#pragma unroll
    for (int r = 0; r < 4; ++r) {
      size_t row = (size_t)t * NN + row0 + w * 16 + quad * 4 + r;
      float4 hn4 = *(const float4*)(p.HN + row * 64 + l16 * 4);
      float4 o4;
      o4.x = acc2[0][r] + b2c[0] + hn4.x;
      o4.y = acc2[1][r] + b2c[1] + hn4.y;
      o4.z = acc2[2][r] + b2c[2] + hn4.z;
      o4.w = acc2[3][r] + b2c[3] + hn4.w;
      *(float4*)(p.H + row * 64 + l16 * 4) = o4;
    }
    return;
  }

  // ---- fused output projection (last layer): out = (hr+ff) @ Wout + bout ----
  // A2 holds ORIGINAL channel order (Wout k is standard).
#pragma unroll
  for (int r = 0; r < 4; ++r) {
    int lrow = w * 16 + quad * 4 + r;
    size_t row = (size_t)t * NN + row0 + lrow;
    float4 hn4 = *(const float4*)(p.HN + row * 64 + l16 * 4);
    float hn[4] = { hn4.x, hn4.y, hn4.z, hn4.w };
#pragma unroll
    for (int ct = 0; ct < 4; ++ct) {
      int col = ct * 16 + l16;
      A2[lrow * LDA + col] = (__bf16)(acc2[ct][r] + b2c[ct] + hn[ct]);
    }
  }
  {
    const unsigned short* Wot = p.Wot + (size_t)t * 4096;  // [64][64] standard
    const unsigned short* bp = Wot + (size_t)brow * 64 + bko;
    uint4 u0 = *(const uint4*)(bp);
    uint4 u1 = *(const uint4*)(bp + 8);
    *(uint4*)&B1s[brow * LDA + bko] = u0;
    *(uint4*)&B1s[brow * LDA + bko + 8] = u1;
  }
  __syncthreads();

  v4f acc3[4];
#pragma unroll
  for (int ct = 0; ct < 4; ++ct)
#pragma unroll
    for (int r = 0; r < 4; ++r) acc3[ct][r] = 0.f;
#pragma unroll
  for (int ks = 0; ks < 2; ++ks) {
    v8bf a = *(v8bf*)&A2[(w * 16 + l16) * LDA + ks * 32 + quad * 8];
#pragma unroll
    for (int ct = 0; ct < 4; ++ct) {
      v8bf bb = *(v8bf*)&B1s[(ct * 16 + l16) * LDA + ks * 32 + quad * 8];
      acc3[ct] = __builtin_amdgcn_mfma_f32_16x16x32_bf16(a, bb, acc3[ct], 0, 0, 0);
    }
  }
  const float* bo = p.bout + t * 64;
#pragma unroll
  for (int ct = 0; ct < 4; ++ct) {
    int col = ct * 16 + l16;
    float bb = bo[col];
#pragma unroll
    for (int r = 0; r < 4; ++r) {
      size_t row = (size_t)t * NN + row0 + w * 16 + quad * 4 + r;
      p.outbuf[row * 64 + col] = acc3[ct][r] + bb;
    }
  }
}

// ======================= edge aggregation + beta + LN (fully permuted, float4 epilogue) =======================
// grid.y = edge type; one wave / dst node; lane = head*16 + c4. Gather loop = R8 (passing).
// Lane c4 owns channels {16i+c4}; ALL hidden-axis tensors permuted -> float4 epilogue.
struct AggPack {
  const unsigned short *Q;   // [2*NN][256] bf16 permuted
  const char *KV;            // [2*NN] rows 512 B permuted
  const float *R;            // [2*NN][64] permuted
  const float *Wb;           // permuted 64-blocks
  const float *Hin;          // permuted
  const float *lng, *lnb;    // permuted
  float* outHR;              // permuted
  const int *rowptr;
  const int *colsrc;
};

__global__ __launch_bounds__(256) void agg_kernel(AggPack p) {
  const int et = blockIdx.y, d = 1 - et;
  int wid = __builtin_amdgcn_readfirstlane(threadIdx.x >> 6);
  int lane = threadIdx.x & 63;
  int node = blockIdx.x * 4 + wid;
  int c4 = lane & 15;
  int cb = ((lane >> 4) << 6) + (c4 << 2);

  const int* rp = p.rowptr + et * (NN + 1);
  const int* cs = p.colsrc + et * EE;
  int start = rp[node], end = rp[node + 1];
  int len = end - start;
  int gnode = d * NN + node;

  uint2 qw = *(const uint2*)(p.Q + ((size_t)gnode << 8) + cb);
  float q0 = blo(qw.x) * 0.125f, q1 = bhi(qw.x) * 0.125f;
  float q2 = blo(qw.y) * 0.125f, q3 = bhi(qw.y) * 0.125f;

  int b[5];
#pragma unroll
  for (int i = 0; i <= 4; ++i) b[i] = start + ((len * i) >> 2);
  float dsum[4] = {0.f, 0.f, 0.f, 0.f};
  float acc[4][4];
#pragma unroll
  for (int s4 = 0; s4 < 4; ++s4)
#pragma unroll
    for (int c = 0; c < 4; ++c) acc[s4][c] = 0.f;

  int maxn = (len + 3) >> 2;
  int last = end - 1;
  for (int it = 0; it < maxn; ++it) {
#pragma unroll
    for (int s4 = 0; s4 < 4; ++s4) {
      int j = b[s4] + it;
      bool act = j < b[s4 + 1];
      int jc = act ? j : last;
      int off = cs[jc];
      const char* rowp = p.KV + off;
      unsigned kw = *(const unsigned*)(rowp + cb);
      unsigned vw = *(const unsigned*)(rowp + 256 + cb);
      v2f kl = __builtin_amdgcn_cvt_pk_f32_fp8((int)kw, false);
      v2f kh = __builtin_amdgcn_cvt_pk_f32_fp8((int)kw, true);
      float pd = q0 * kl[0] + q1 * kl[1] + q2 * kh[0] + q3 * kh[1];
      pd += __shfl_xor(pd, 1);
      pd += __shfl_xor(pd, 2);
      pd += __shfl_xor(pd, 4);
      pd += __shfl_xor(pd, 8);
      float wgt = act ? __expf(pd) : 0.f;
      v2f vl = __builtin_amdgcn_cvt_pk_f32_fp8((int)vw, false);
      v2f vh = __builtin_amdgcn_cvt_pk_f32_fp8((int)vw, true);
      dsum[s4] += wgt;
      acc[s4][0] += wgt * vl[0];
      acc[s4][1] += wgt * vl[1];
      acc[s4][2] += wgt * vh[0];
      acc[s4][3] += wgt * vh[1];
    }
  }
  // o_[i] = channel 16*i + c4 (within head, then head-mean)
  float dn = (dsum[0] + dsum[1]) + (dsum[2] + dsum[3]);
  float o_[4];
#pragma unroll
  for (int i = 0; i < 4; ++i)
    o_[i] = (acc[0][i] + acc[1][i]) + (acc[2][i] + acc[3][i]);

  float inv = (len > 0) ? (0.25f / dn) : 0.f;
#pragma unroll
  for (int i = 0; i < 4; ++i) {
    float a = o_[i] * inv;
    a += __shfl_xor(a, 16);
    a += __shfl_xor(a, 32);
    o_[i] = a;
  }

  // float4 epilogue (all hidden-axis buffers permuted; position 4*c4+i = channel 16i+c4)
  float4 r4 = *(const float4*)(p.R + (size_t)gnode * 64 + c4 * 4);
  float4 h4 = *(const float4*)(p.Hin + (size_t)gnode * 64 + c4 * 4);
  float rr[4] = { r4.x, r4.y, r4.z, r4.w };
  float hh[4] = { h4.x, h4.y, h4.z, h4.w };

  const float* wb = p.Wb + et * 192;
  float4 wo4 = *(const float4*)(wb + c4 * 4);
  float4 wr4 = *(const float4*)(wb + 64 + c4 * 4);
  float4 wd4 = *(const float4*)(wb + 128 + c4 * 4);
  float wo[4] = { wo4.x, wo4.y, wo4.z, wo4.w };
  float wr[4] = { wr4.x, wr4.y, wr4.z, wr4.w };
  float wd[4] = { wd4.x, wd4.y, wd4.z, wd4.w };
  float part = 0.f;
#pragma unroll
  for (int i = 0; i < 4; ++i)
    part += o_[i] * wo[i] + rr[i] * wr[i] + (o_[i] - rr[i]) * wd[i];
  part += __shfl_xor(part, 1);
  part += __shfl_xor(part, 2);
  part += __shfl_xor(part, 4);
  part += __shfl_xor(part, 8);
  float beta = 1.f / (1.f + __expf(-part));

  float y[4];
  float sa = 0.f, sb = 0.f;
#pragma unroll
  for (int i = 0; i < 4; ++i) {
    float v = hh[i] + beta * rr[i] + (1.f - beta) * o_[i];
    y[i] = v;
    sa += v;
    sb += v * v;
  }
  sa += __shfl_xor(sa, 1); sb += __shfl_xor(sb, 1);
  sa += __shfl_xor(sa, 2); sb += __shfl_xor(sb, 2);
  sa += __shfl_xor(sa, 4); sb += __shfl_xor(sb, 4);
  sa += __shfl_xor(sa, 8); sb += __shfl_xor(sb, 8);
  float mu = sa * (1.f / 64.f);
  float var = sb * (1.f / 64.f) - mu * mu;
  float rs = rsqrtf(var + 1e-5f);
  if (lane < 16) {
    float4 g4 = *(const float4*)(p.lng + d * 64 + c4 * 4);
    float4 bb4 = *(const float4*)(p.lnb + d * 64 + c4 * 4);
    float4 res;
    res.x = (y[0] - mu) * rs * g4.x + bb4.x;
    res.y = (y[1] - mu) * rs * g4.y + bb4.y;
    res.z = (y[2] - mu) * rs * g4.z + bb4.z;
    res.w = (y[3] - mu) * rs * g4.w + bb4.w;
    *(float4*)(p.outHR + (size_t)gnode * 64 + c4 * 4) = res;
  }
}

// ======================= host =======================
static void add_desc(GemmPack& p, const float* A, const unsigned short* Bt,
                     const float* bias, const float* bias2, const float* add,
                     void* C, int Nc, int Cld, int gelu, int otype) {
  GemmDesc& g = p.d[p.nd++];
  g.A = A; g.Bt = Bt; g.bias = bias; g.bias2 = bias2; g.add = add; g.C = (char*)C;
  g.Ncols = Nc; g.Cld = Cld; g.ntiles = Nc / 64;
  g.gelu = gelu; g.otype = otype;
}

extern "C" void kernel_launch(void* const* d_in, const int* in_sizes, int n_in,
                              void* d_out, int out_size, void* d_ws, size_t ws_size,
                              hipStream_t stream) {
  const float* x        = (const float*)d_in[0];
  const int*   ei       = (const int*)d_in[1];
  const float* W_in     = (const float*)d_in[2];
  const float* b_in     = (const float*)d_in[3];
  const float* type_emb = (const float*)d_in[4];
  const float* pos      = (const float*)d_in[5];
  const float* Wq       = (const float*)d_in[6];
  const float* bq       = (const float*)d_in[7];
  const float* Wk       = (const float*)d_in[8];
  const float* bk       = (const float*)d_in[9];
  const float* Wv       = (const float*)d_in[10];
  const float* bv       = (const float*)d_in[11];
  const float* Wskip    = (const float*)d_in[12];
  const float* bskip    = (const float*)d_in[13];
  const float* Wbeta    = (const float*)d_in[14];
  const float* ln_g     = (const float*)d_in[15];
  const float* ln_b     = (const float*)d_in[16];
  const float* ff_W1    = (const float*)d_in[17];
  const float* ff_b1    = (const float*)d_in[18];
  const float* ff_W2    = (const float*)d_in[19];
  const float* ff_b2    = (const float*)d_in[20];
  const float* W_out    = (const float*)d_in[21];
  const float* b_out    = (const float*)d_in[22];
  float* out = (float*)d_out;

  int*   wsi = (int*)d_ws;
  float* wsf = (float*)d_ws;
  int* cnt    = wsi + OFF_CNT;
  int* fill   = wsi + OFF_FILL;
  int* rowptr = wsi + OFF_ROWPTR;
  int* colsrc = wsi + OFF_COLSRC;
  float* H  = wsf + OFF_H;
  float* HN = wsf + OFF_HN;
  unsigned short* Qb = (unsigned short*)(wsf + OFF_Q);
  char* KVb = (char*)(wsf + OFF_KV);
  float* Rb = wsf + OFF_R;
  unsigned short* wt = (unsigned short*)(wsf + OFF_WT);
  float* wbp  = wsf + OFF_WBP;
  float* lngp = wsf + OFF_LNG;
  float* lnbp = wsf + OFF_LNB;

  // ---- weight prep (transpose + bf16 [+ k-perm]), once per launch ----
  {
    PrepPack pp{};
    int nd = 0;
    for (int we = 0; we < 4; ++we) {
      pp.d[nd++] = { Wq + (size_t)we * 16384, wt + WT_Q + we * 16384, 6, 16384, 1 };
      pp.d[nd++] = { Wk + (size_t)we * 16384, wt + WT_K + we * 16384, 6, 16384, 1 };
      pp.d[nd++] = { Wv + (size_t)we * 16384, wt + WT_V + we * 16384, 6, 16384, 1 };
      pp.d[nd++] = { Wskip + (size_t)we * 4096, wt + WT_S + we * 4096, 6, 4096, 1 };
      pp.d[nd++] = { ff_W1 + (size_t)we * 16384, wt + WT_W1 + we * 16384, 6, 16384, 1 };
      pp.d[nd++] = { ff_W2 + (size_t)we * 16384, wt + WT_W2 + we * 16384, 8, 16384, 0 };
    }
    for (int t = 0; t < 2; ++t) {
      pp.d[nd++] = { W_in + (size_t)t * 4096, wt + WT_IN + t * 4096, 6, 4096, 0 };
      pp.d[nd++] = { W_out + (size_t)t * 4096, wt + WT_WO + t * 4096, 6, 4096, 0 };
    }
    prep_kernel<<<dim3(64, nd), dim3(256), 0, stream>>>(pp);
  }
  // ---- f32 64-block permute: Wbeta, ln_g, ln_b ----
  {
    PermPack pm{};
    pm.d[0] = { Wbeta, wbp, 768 };
    pm.d[1] = { ln_g, lngp, 256 };
    pm.d[2] = { ln_b, lnbp, 256 };
    perm_kernel<<<dim3(3, 3), dim3(256), 0, stream>>>(pm);
  }

  // ---- CSR build ----
  hipMemsetAsync(cnt, 0, 2 * NN * sizeof(int), stream);
  count_kernel<<<dim3(2 * EE / 256), dim3(256), 0, stream>>>(ei, cnt);
  scan_kernel<<<dim3(2), dim3(1024), 0, stream>>>(cnt, rowptr, fill);
  scatter_kernel<<<dim3(2 * EE / 256), dim3(256), 0, stream>>>(ei, fill, colsrc);

  // ---- input projection (x standard-k; H written permuted) ----
  {
    GemmPack p{};
    for (int t = 0; t < 2; ++t)
      add_desc(p, x + (size_t)t * NN * 64, wt + WT_IN + t * 4096,
               b_in + t * 64, type_emb + t * 64, pos + (size_t)t * NN * 64,
               H + (size_t)t * NN * 64, 64, 256, 0, 0);
    gemm_mfma<<<dim3(128, p.nd), dim3(256), 0, stream>>>(p);
  }

  for (int l = 0; l < 2; ++l) {
    // one batched GEMM for both edge types: q,k,v,skip x 2 (A = permuted H, k-perm weights)
    {
      GemmPack p{};
      for (int et = 0; et < 2; ++et) {
        int s = et, d = 1 - et;
        int we = l * 2 + et;
        const float* hs = H + (size_t)s * NN * 64;
        const float* hd = H + (size_t)d * NN * 64;
        add_desc(p, hd, wt + WT_Q + we * 16384, bq + we * 256,
                 nullptr, nullptr, (char*)Qb + (size_t)d * NN * 512, 256, 512, 0, 1);
        add_desc(p, hs, wt + WT_K + we * 16384, bk + we * 256,
                 nullptr, nullptr, KVb + (size_t)s * NN * 512, 256, 512, 0, 2);
        add_desc(p, hs, wt + WT_V + we * 16384, bv + we * 256,
                 nullptr, nullptr, KVb + (size_t)s * NN * 512 + 256, 256, 512, 0, 2);
        add_desc(p, hd, wt + WT_S + we * 4096, bskip + we * 64,
                 nullptr, nullptr, Rb + (size_t)d * NN * 64, 64, 256, 0, 0);
      }
      gemm_mfma<<<dim3(128, p.nd), dim3(256), 0, stream>>>(p);
    }

    AggPack ap;
    ap.Q = Qb; ap.KV = KVb; ap.R = Rb;
    ap.Wb = wbp + l * 2 * 192;
    ap.Hin = H;
    ap.lng = lngp + l * 128;
    ap.lnb = lnbp + l * 128;
    ap.outHR = HN;
    ap.rowptr = rowptr;
    ap.colsrc = colsrc;
    agg_kernel<<<dim3(NN / 4, 2), dim3(256), 0, stream>>>(ap);

    FFPack fp;
    fp.HN = HN;
    fp.W1t = wt + WT_W1 + l * 2 * 16384;
    fp.W2t = wt + WT_W2 + l * 2 * 16384;
    fp.Wot = wt + WT_WO;
    fp.b1 = ff_b1 + l * 2 * 256;
    fp.b2 = ff_b2 + l * 2 * 64;
    fp.bout = b_out;
    fp.H  = H;
    fp.outbuf = (l == 1) ? out : nullptr;   // fuse output projection into last FF
    ff_fused<<<dim3(NN / 64, 2), dim3(256), 0, stream>>>(fp);
  }
}